// Round 2
// baseline (244.238 us; speedup 1.0000x reference)
//
#include <hip/hip_runtime.h>
#include <hip/hip_cooperative_groups.h>
#include <cmath>

namespace cg = cooperative_groups;

#define E_EXPERTS 16
#define D_DIM 2048
#define H_DIM 2048
#define NBLOCKS 1024   // 4 blocks/CU * 256 CUs; co-resident under launch_bounds(256,4)

// One fused cooperative kernel:
//   phase 0: blocks 0..15 compute gate logits (one expert each) -> ws
//   grid.sync()
//   every block: top-2 + normalized gates from the 16 logits (redundant, trivial)
//   phase 1: 4096 waves == one wave per (k,row) of h = tanh(W1[idx]x + b1)
//   grid.sync()
//   phase 2: 4096 waves == one wave per (output o, expert k); LDS-combine -> out
__global__ __launch_bounds__(256, 4) void moe_fused(
    const float* __restrict__ x,  const float* __restrict__ Wg,
    const float* __restrict__ bg, const float* __restrict__ W1,
    const float* __restrict__ b1, const float* __restrict__ W2,
    const float* __restrict__ b2, float* __restrict__ out,
    float* __restrict__ ws) {
    cg::grid_group grid = cg::this_grid();
    float* logits = ws;        // [16]
    float* h      = ws + 16;   // [2][H_DIM], 64B-aligned

    const int tid  = threadIdx.x;
    const int wave = tid >> 6;
    const int lane = tid & 63;
    const int blk  = blockIdx.x;

    __shared__ float sred[4];
    __shared__ float slog[E_EXPERTS];

    // ---------------- phase 0: gate logits ----------------
    if (blk < E_EXPERTS) {
        const float4* wrow = (const float4*)(Wg + (size_t)blk * D_DIM);
        const float4* xv   = (const float4*)x;
        float acc = 0.f;
#pragma unroll
        for (int i = 0; i < 2; ++i) {            // 512 float4 over 256 threads
            float4 w  = wrow[tid + i * 256];
            float4 xx = xv[tid + i * 256];
            acc += w.x * xx.x + w.y * xx.y + w.z * xx.z + w.w * xx.w;
        }
#pragma unroll
        for (int off = 32; off; off >>= 1) acc += __shfl_down(acc, off, 64);
        if (lane == 0) sred[wave] = acc;
        __syncthreads();
        if (tid == 0) logits[blk] = sred[0] + sred[1] + sred[2] + sred[3] + bg[blk];
    }
    grid.sync();

    // ---------------- every block: top-2 from logits ----------------
    if (tid < E_EXPERTS) slog[tid] = logits[tid];
    __syncthreads();

    float m = -1e30f;
#pragma unroll
    for (int e = 0; e < E_EXPERTS; ++e) m = fmaxf(m, slog[e]);
    float p[E_EXPERTS];
    float s = 0.f;
#pragma unroll
    for (int e = 0; e < E_EXPERTS; ++e) { p[e] = __expf(slog[e] - m); s += p[e]; }
    int i0 = 0; float v0 = p[0];
#pragma unroll
    for (int e = 1; e < E_EXPERTS; ++e) if (p[e] > v0) { v0 = p[e]; i0 = e; }
    int i1 = -1; float v1 = -1.f;
#pragma unroll
    for (int e = 0; e < E_EXPERTS; ++e) {
        if (e == i0) continue;
        if (p[e] > v1) { v1 = p[e]; i1 = e; }
    }
    float g0 = v0 / s, g1 = v1 / s;
    float denom = g0 + g1 + 1e-6f;
    const float tk0 = g0 / denom, tk1 = g1 / denom;

    // ---------------- phase 1: h rows (one wave per row) ----------------
    {
        const int gw = blk * 4 + wave;           // 0..4095
        const int k  = gw >> 11;                 // expert slot
        const int r  = gw & (H_DIM - 1);
        const int e  = (k == 0) ? i0 : i1;
        const float4* wrow = (const float4*)(W1 + ((size_t)e * H_DIM + r) * D_DIM);
        const float4* xv   = (const float4*)x;
        float acc = 0.f;
#pragma unroll
        for (int i = 0; i < D_DIM / 4 / 64; ++i) {   // 8 iters, 1KB/instr coalesced
            float4 w  = wrow[lane + i * 64];
            float4 xx = xv[lane + i * 64];
            acc += w.x * xx.x + w.y * xx.y + w.z * xx.z + w.w * xx.w;
        }
#pragma unroll
        for (int off = 32; off; off >>= 1) acc += __shfl_down(acc, off, 64);
        if (lane == 0) h[k * H_DIM + r] = tanhf(acc + b1[(size_t)e * H_DIM + r]);
    }
    grid.sync();

    // ---------------- phase 2: outputs (one wave per (o, k)) ----------------
    {
        const int o = blk * 2 + (wave & 1);
        const int k = wave >> 1;
        const int e = (k == 0) ? i0 : i1;
        const float4* wrow = (const float4*)(W2 + ((size_t)e * H_DIM + o) * H_DIM);
        const float4* hv   = (const float4*)(h + k * H_DIM);
        float acc = 0.f;
#pragma unroll
        for (int i = 0; i < H_DIM / 4 / 64; ++i) {
            float4 w  = wrow[lane + i * 64];
            float4 hh = hv[lane + i * 64];
            acc += w.x * hh.x + w.y * hh.y + w.z * hh.z + w.w * hh.w;
        }
#pragma unroll
        for (int off = 32; off; off >>= 1) acc += __shfl_down(acc, off, 64);
        if (lane == 0) sred[wave] = acc;         // (k*2 + parity) slot
        __syncthreads();
        if (tid < 2) {
            const int oo = blk * 2 + tid;
            float eo0 = sred[tid]     + b2[(size_t)i0 * H_DIM + oo];
            float eo1 = sred[2 + tid] + b2[(size_t)i1 * H_DIM + oo];
            out[oo] = tk0 * eo0 + tk1 * eo1;
        }
    }
}

extern "C" void kernel_launch(void* const* d_in, const int* in_sizes, int n_in,
                              void* d_out, int out_size, void* d_ws, size_t ws_size,
                              hipStream_t stream) {
    const float* x  = (const float*)d_in[0];
    const float* Wg = (const float*)d_in[1];
    const float* bg = (const float*)d_in[2];
    const float* W1 = (const float*)d_in[3];
    const float* b1 = (const float*)d_in[4];
    const float* W2 = (const float*)d_in[5];
    const float* b2 = (const float*)d_in[6];
    float* out  = (float*)d_out;
    float* ws_f = (float*)d_ws;

    void* args[] = {(void*)&x, (void*)&Wg, (void*)&bg, (void*)&W1, (void*)&b1,
                    (void*)&W2, (void*)&b2, (void*)&out, (void*)&ws_f};
    hipLaunchCooperativeKernel((void*)moe_fused, dim3(NBLOCKS), dim3(256),
                               args, 0, stream);
}

// Round 3
// 24.335 us; speedup vs baseline: 10.0366x; 10.0366x over previous
//
#include <hip/hip_runtime.h>
#include <cmath>

#define E_EXPERTS 16
#define D_DIM 2048
#define H_DIM 2048

// ---------------------------------------------------------------------------
// Kernel A: fused gate + h.
// 1024 blocks x 256 threads (4 waves). EVERY block redundantly computes the
// gate (16 logits -> softmax -> top-2 -> normalized gates) from Wg/x -- Wg is
// 131 KB and L2/L3-resident after the first blocks touch it, so this preamble
// costs ~1-2 us and overlaps across blocks. Then the block's 4 waves each
// compute one h row: h[k][r] = tanh(W1[e_k][r] . x + b1[e_k][r]).
// Block 0 publishes tkg[2]/idx[2] to ws for kernel B.
// ---------------------------------------------------------------------------
__global__ __launch_bounds__(256) void moe_gate_h(
    const float* __restrict__ x,  const float* __restrict__ Wg,
    const float* __restrict__ bg, const float* __restrict__ W1,
    const float* __restrict__ b1, float* __restrict__ ws) {
    float* tkg = ws;                 // [2]
    int*   idx = ((int*)ws) + 2;     // [2]
    float* h   = ws + 16;            // [2][H_DIM]

    const int tid  = threadIdx.x;
    const int wave = tid >> 6;
    const int lane = tid & 63;
    const int blk  = blockIdx.x;

    __shared__ float slog[E_EXPERTS];

    // ---- redundant gate: wave w computes logits for experts 4w..4w+3 ----
    const float4* xv = (const float4*)x;
    float4 xx[8];
#pragma unroll
    for (int i = 0; i < 8; ++i) xx[i] = xv[lane + i * 64];

#pragma unroll
    for (int q = 0; q < 4; ++q) {
        const int e = wave * 4 + q;
        const float4* wrow = (const float4*)(Wg + (size_t)e * D_DIM);
        float acc = 0.f;
#pragma unroll
        for (int i = 0; i < 8; ++i) {
            float4 w = wrow[lane + i * 64];
            acc += w.x * xx[i].x + w.y * xx[i].y + w.z * xx[i].z + w.w * xx[i].w;
        }
#pragma unroll
        for (int off = 32; off; off >>= 1) acc += __shfl_down(acc, off, 64);
        if (lane == 0) slog[e] = acc + bg[e];
    }
    __syncthreads();

    // ---- every thread: softmax + top-2 + normalized gates (identical) ----
    float m = -1e30f;
#pragma unroll
    for (int e = 0; e < E_EXPERTS; ++e) m = fmaxf(m, slog[e]);
    float p[E_EXPERTS];
    float s = 0.f;
#pragma unroll
    for (int e = 0; e < E_EXPERTS; ++e) { p[e] = __expf(slog[e] - m); s += p[e]; }
    int i0 = 0; float v0 = p[0];
#pragma unroll
    for (int e = 1; e < E_EXPERTS; ++e) if (p[e] > v0) { v0 = p[e]; i0 = e; }
    int i1 = -1; float v1 = -1.f;
#pragma unroll
    for (int e = 0; e < E_EXPERTS; ++e) {
        if (e == i0) continue;
        if (p[e] > v1) { v1 = p[e]; i1 = e; }
    }
    float g0 = v0 / s, g1 = v1 / s;
    float denom = g0 + g1 + 1e-6f;

    if (blk == 0 && tid == 0) {
        tkg[0] = g0 / denom;
        tkg[1] = g1 / denom;
        idx[0] = i0;
        idx[1] = i1;
    }

    // ---- h rows: one wave per (k, r) ----
    const int gw = blk * 4 + wave;          // 0..4095
    const int k  = gw >> 11;                // expert slot
    const int r  = gw & (H_DIM - 1);
    const int e  = (k == 0) ? i0 : i1;

    const float4* wrow = (const float4*)(W1 + ((size_t)e * H_DIM + r) * D_DIM);
    float acc = 0.f;
#pragma unroll
    for (int i = 0; i < 8; ++i) {           // 1 KB/instr coalesced
        float4 w = wrow[lane + i * 64];
        acc += w.x * xx[i].x + w.y * xx[i].y + w.z * xx[i].z + w.w * xx[i].w;
    }
#pragma unroll
    for (int off = 32; off; off >>= 1) acc += __shfl_down(acc, off, 64);
    if (lane == 0) h[k * H_DIM + r] = tanhf(acc + b1[(size_t)e * H_DIM + r]);
}

// ---------------------------------------------------------------------------
// Kernel B: out[o] = sum_k tkg[k] * (W2[e_k][o] . h[k] + b2[e_k][o]).
// 1024 blocks x 256 threads; one wave per (o, k) pair (4096 waves), LDS
// combine of the two expert partials per output.
// ---------------------------------------------------------------------------
__global__ __launch_bounds__(256) void moe_out(
    const float* __restrict__ W2, const float* __restrict__ b2,
    const float* __restrict__ ws, float* __restrict__ out) {
    const float* tkg = ws;
    const int*   idx = ((const int*)ws) + 2;
    const float* h   = ws + 16;

    const int tid  = threadIdx.x;
    const int wave = tid >> 6;
    const int lane = tid & 63;
    const int blk  = blockIdx.x;

    const int o = blk * 2 + (wave & 1);     // 0..2047
    const int k = wave >> 1;                // 0/1
    const int e = idx[k];

    __shared__ float sred[4];

    const float4* wrow = (const float4*)(W2 + ((size_t)e * H_DIM + o) * H_DIM);
    const float4* hv   = (const float4*)(h + k * H_DIM);
    float acc = 0.f;
#pragma unroll
    for (int i = 0; i < 8; ++i) {
        float4 w  = wrow[lane + i * 64];
        float4 hh = hv[lane + i * 64];
        acc += w.x * hh.x + w.y * hh.y + w.z * hh.z + w.w * hh.w;
    }
#pragma unroll
    for (int off = 32; off; off >>= 1) acc += __shfl_down(acc, off, 64);
    if (lane == 0) sred[wave] = acc;
    __syncthreads();

    if (tid < 2) {
        const int oo = blk * 2 + tid;
        const int e0 = idx[0], e1 = idx[1];
        float eo0 = sred[tid]     + b2[(size_t)e0 * H_DIM + oo];
        float eo1 = sred[2 + tid] + b2[(size_t)e1 * H_DIM + oo];
        out[oo] = tkg[0] * eo0 + tkg[1] * eo1;
    }
}

extern "C" void kernel_launch(void* const* d_in, const int* in_sizes, int n_in,
                              void* d_out, int out_size, void* d_ws, size_t ws_size,
                              hipStream_t stream) {
    const float* x  = (const float*)d_in[0];
    const float* Wg = (const float*)d_in[1];
    const float* bg = (const float*)d_in[2];
    const float* W1 = (const float*)d_in[3];
    const float* b1 = (const float*)d_in[4];
    const float* W2 = (const float*)d_in[5];
    const float* b2 = (const float*)d_in[6];
    float* out  = (float*)d_out;
    float* ws_f = (float*)d_ws;

    moe_gate_h<<<1024, 256, 0, stream>>>(x, Wg, bg, W1, b1, ws_f);
    moe_out<<<1024, 256, 0, stream>>>(W2, b2, ws_f, out);
}